// Round 6
// baseline (283.210 us; speedup 1.0000x reference)
//
#include <hip/hip_runtime.h>
#include <hip/hip_fp8.h>
#include <stdint.h>
#include <cmath>

using f32x4 = __attribute__((ext_vector_type(4))) float;
using i32x4 = __attribute__((ext_vector_type(4))) int;
using i32x8 = __attribute__((ext_vector_type(8))) int;

#define FP8MAX 448.0f

// ---------------------------------------------------------------- helpers
__device__ __forceinline__ void gload_lds16(const void* g, void* l) {
  __builtin_amdgcn_global_load_lds(
      (const __attribute__((address_space(1))) unsigned int*)g,
      (__attribute__((address_space(3))) unsigned int*)l,
      16, 0, 0);
}

__device__ __forceinline__ uint8_t to_fp8(float v) {
  __hip_fp8_e4m3 q(fminf(fmaxf(v, -FP8MAX), FP8MAX));  // saturating RNE, OCP e4m3fn
  return q.__x;
}

// ---------------------------------------------------------------- W convert -> fp8 bytes (self-detecting)
// Detects d_in[1] representation from the first 4096 f32-interpreted values
// (16 KB, valid for any candidate format; L2-shared across blocks):
//   flag 2: float32 of fp8-exact values; 1: bf16; 0: raw fp8 bytes.
// Also zeroes the amax slot (stream-ordered before amax_kernel).
__global__ void wconv(const uint8_t* __restrict__ w, uint8_t* __restrict__ q,
                      unsigned int* __restrict__ amax_u, int n) {
  if (blockIdx.x == 0 && threadIdx.x == 0) amax_u[0] = 0u;

  const float* wf = (const float*)w;
  const unsigned short* wh = (const unsigned short*)w;
  int f32ok = 1, bf16ok = 1;
  for (int i = threadIdx.x; i < 4096; i += 256) {
    float v = wf[i];
    if (!(isfinite(v) && fabsf(v) <= FP8MAX)) f32ok = 0;
    else { __hip_fp8_e4m3 qq(v); if ((float)qq != v) f32ok = 0; }
    float hv = __uint_as_float(((unsigned int)wh[i]) << 16);
    if (!(isfinite(hv) && fabsf(hv) <= FP8MAX)) bf16ok = 0;
    else { __hip_fp8_e4m3 qh(hv); if ((float)qh != hv) bf16ok = 0; }
  }
  __shared__ int sf, sb;
  if (threadIdx.x == 0) { sf = 1; sb = 1; }
  __syncthreads();
  if (!f32ok) atomicAnd(&sf, 0);
  if (!bf16ok) atomicAnd(&sb, 0);
  __syncthreads();
  unsigned int f = sf ? 2u : (sb ? 1u : 0u);

  int i0 = (blockIdx.x * blockDim.x + threadIdx.x) * 4;
  if (i0 >= n) return;
  uint32_t out;
  if (f == 2) {
    float4 v = *(const float4*)((const float*)w + i0);
    out = (uint32_t)to_fp8(v.x) | ((uint32_t)to_fp8(v.y) << 8) |
          ((uint32_t)to_fp8(v.z) << 16) | ((uint32_t)to_fp8(v.w) << 24);
  } else if (f == 1) {
    ushort4 h = *(const ushort4*)((const unsigned short*)w + i0);
    float a = __uint_as_float(((unsigned int)h.x) << 16);
    float b = __uint_as_float(((unsigned int)h.y) << 16);
    float c = __uint_as_float(((unsigned int)h.z) << 16);
    float d = __uint_as_float(((unsigned int)h.w) << 16);
    out = (uint32_t)to_fp8(a) | ((uint32_t)to_fp8(b) << 8) |
          ((uint32_t)to_fp8(c) << 16) | ((uint32_t)to_fp8(d) << 24);
  } else {
    out = *(const uint32_t*)(w + i0);
  }
  *(uint32_t*)(q + i0) = out;
}

// ---------------------------------------------------------------- pass 1: amax = max(|x|)
__global__ void amax_kernel(const float* __restrict__ x, size_t n4,
                            unsigned int* __restrict__ amax_u) {
  const float4* x4 = (const float4*)x;
  float m = 0.0f;
  size_t stride = (size_t)gridDim.x * blockDim.x;
  for (size_t i = (size_t)blockIdx.x * blockDim.x + threadIdx.x; i < n4; i += stride) {
    float4 v = x4[i];
    m = fmaxf(m, fmaxf(fmaxf(fabsf(v.x), fabsf(v.y)),
                       fmaxf(fabsf(v.z), fabsf(v.w))));
  }
  #pragma unroll
  for (int off = 32; off > 0; off >>= 1)
    m = fmaxf(m, __shfl_xor(m, off));
  __shared__ float sm[16];
  int wid = threadIdx.x >> 6;
  if ((threadIdx.x & 63) == 0) sm[wid] = m;
  __syncthreads();
  if (threadIdx.x == 0) {
    int nw = blockDim.x >> 6;
    float r = sm[0];
    for (int i = 1; i < nw; i++) r = fmaxf(r, sm[i]);
    atomicMax(amax_u, __float_as_uint(r));  // non-negative float bits order-preserving
  }
}

// ---------------------------------------------------------------- pass 2: quantize x -> fp8
__global__ void quant_kernel(const float* __restrict__ x,
                             uint8_t* __restrict__ q,
                             const float* __restrict__ amax_p, size_t n16) {
  float amax = fmaxf(amax_p[0], 1e-12f);
  float scale = FP8MAX / amax;        // reference: FP8_MAX / clip(amax)
  const float4* x4 = (const float4*)x;
  uint4* q16 = (uint4*)q;
  size_t stride = (size_t)gridDim.x * blockDim.x;
  for (size_t i = (size_t)blockIdx.x * blockDim.x + threadIdx.x; i < n16; i += stride) {
    uint32_t w[4];
    #pragma unroll
    for (int j = 0; j < 4; j++) {
      float4 v = x4[i * 4 + j];
      w[j] = (uint32_t)to_fp8(v.x * scale) | ((uint32_t)to_fp8(v.y * scale) << 8) |
             ((uint32_t)to_fp8(v.z * scale) << 16) | ((uint32_t)to_fp8(v.w * scale) << 24);
    }
    uint4 o; o.x = w[0]; o.y = w[1]; o.z = w[2]; o.w = w[3];
    q16[i] = o;
  }
}

// ---------------------------------------------------------------- pass 3: MX-fp8 GEMM (unit scales), 2-phase pipeline
// C[M,N] = s * A[M,K] x B[N,K]^T.  128x128 tile, BK=128, 4 waves (2x2),
// mfma_scale_f32_16x16x128_f8f6f4 with E8M0 0x7F (=1.0).
// T3-minimum double-buffer: stage(t+1) -> compute(t) -> __syncthreads()
// (one barrier/K-step; syncthreads' implicit vmcnt(0) is the drain, and the
// global-load latency hides under this tile's ds_read+MFMA).
// T2 swizzle under global_load_lds (rule #21): linear LDS dest, global
// source chunk ^= (row&7), reads XOR the same way.
#define BM 128
#define BN 128
#define BK 128

__global__ __launch_bounds__(256) void gemm_fp8(
    const uint8_t* __restrict__ A,   // [M,K] fp8
    const uint8_t* __restrict__ B,   // [N,K] fp8
    float* __restrict__ C,           // [M,N] f32
    const float* __restrict__ amax_p,
    const float* __restrict__ wscale_p,
    int M, int N, int K) {
  __shared__ uint8_t lds_a[2][BM * BK];  // 2 x 16 KB
  __shared__ uint8_t lds_b[2][BN * BK];  // 2 x 16 KB

  // bijective XCD swizzle (gridDim % 8 == 0); 8 blocks sharing an A-strip
  // get consecutive swz -> same XCD -> strip fetched once per XCD.
  int nwg = gridDim.x;
  int cpx = nwg >> 3;
  int swz = (blockIdx.x & 7) * cpx + (blockIdx.x >> 3);

  int nstrips = N / BN;               // 8
  int bm = (swz / nstrips) * BM;
  int bn = (swz % nstrips) * BN;

  int t = threadIdx.x;
  int lane = t & 63;
  int wave = t >> 6;
  int wm = (wave >> 1) * 64;
  int wn = (wave & 1) * 64;

  float amax = fmaxf(amax_p[0], 1e-12f);
  float scale = FP8MAX / amax;
  float s = (1.0f / scale) * wscale_p[0];   // inv_act_scale * weight_scale

  f32x4 acc[4][4] = {};

  // staging geometry: pass p covers rows p*32..p*32+31; thread t -> row
  // p*32+(t>>3), LDS linear dest (wave*1024 + p*4096 + lane*16), global
  // 16B-chunk (t&7)^(row&7).
  const int rt = t >> 3;
  const int ct = t & 7;
  const int stoff = wave * 1024;

  // fragment read constants
  const int lr = lane & 15;           // row-in-fragment
  const int x7 = lr & 7;              // rows wm+i*16+lr have row&7 == lr&7
  const int g2 = (lane >> 4) << 1;    // 16B-chunk pair base: 0,2,4,6
  const int c0 = ((g2 ^ x7) << 4);
  const int c1 = (((g2 + 1) ^ x7) << 4);
  int abase[4], bbase[4];
  #pragma unroll
  for (int i = 0; i < 4; i++) abase[i] = (wm + i * 16 + lr) * BK;
  #pragma unroll
  for (int j = 0; j < 4; j++) bbase[j] = (wn + j * 16 + lr) * BK;

  auto stage = [&](uint8_t* dstA, uint8_t* dstB, int k0) {
    #pragma unroll
    for (int p = 0; p < 4; ++p) {
      int r = p * 32 + rt;
      int gc = (ct ^ (r & 7)) * 16;
      gload_lds16(A + (size_t)(bm + r) * K + k0 + gc, dstA + stoff + p * 4096);
      gload_lds16(B + (size_t)(bn + r) * K + k0 + gc, dstB + stoff + p * 4096);
    }
  };

  auto compute = [&](const uint8_t* baseA, const uint8_t* baseB) {
    i32x8 af[4], bf[4];
    #pragma unroll
    for (int i = 0; i < 4; i++) {
      i32x4 lo = *(const i32x4*)(baseA + abase[i] + c0);
      i32x4 hi = *(const i32x4*)(baseA + abase[i] + c1);
      af[i] = (i32x8){lo.x, lo.y, lo.z, lo.w, hi.x, hi.y, hi.z, hi.w};
    }
    #pragma unroll
    for (int j = 0; j < 4; j++) {
      i32x4 lo = *(const i32x4*)(baseB + bbase[j] + c0);
      i32x4 hi = *(const i32x4*)(baseB + bbase[j] + c1);
      bf[j] = (i32x8){lo.x, lo.y, lo.z, lo.w, hi.x, hi.y, hi.z, hi.w};
    }
    #pragma unroll
    for (int i = 0; i < 4; i++)
      #pragma unroll
      for (int j = 0; j < 4; j++)
        acc[i][j] = __builtin_amdgcn_mfma_scale_f32_16x16x128_f8f6f4(
            af[i], bf[j], acc[i][j],
            0 /*A=fp8*/, 0 /*B=fp8*/,
            0, 0x7f7f7f7f,   // scale_A opsel, E8M0 1.0
            0, 0x7f7f7f7f);  // scale_B opsel, E8M0 1.0
  };

  const int KITERS = K / BK;          // 8 (even)
  stage(lds_a[0], lds_b[0], 0);
  __syncthreads();                    // drain prologue loads

  for (int it = 0; it < KITERS; it += 2) {
    if (it + 1 < KITERS) stage(lds_a[1], lds_b[1], (it + 1) * BK);
    compute(lds_a[0], lds_b[0]);
    __syncthreads();                  // drain buf1 loads + protect buf0 reuse
    if (it + 2 < KITERS) stage(lds_a[0], lds_b[0], (it + 2) * BK);
    compute(lds_a[1], lds_b[1]);
    __syncthreads();                  // drain buf0 loads + protect buf1 reuse
  }

  // epilogue: C/D layout col=lane&15, row=(lane>>4)*4+reg (shape-determined)
  #pragma unroll
  for (int i = 0; i < 4; i++) {
    #pragma unroll
    for (int j = 0; j < 4; j++) {
      int row = bm + wm + i * 16 + (lane >> 4) * 4;
      int col = bn + wn + j * 16 + (lane & 15);
      #pragma unroll
      for (int r = 0; r < 4; r++)
        C[(size_t)(row + r) * N + col] = acc[i][j][r] * s;
    }
  }
}

// ---------------------------------------------------------------- launch
extern "C" void kernel_launch(void* const* d_in, const int* in_sizes, int n_in,
                              void* d_out, int out_size, void* d_ws, size_t ws_size,
                              hipStream_t stream) {
  const float* x = (const float*)d_in[0];
  const uint8_t* wraw = (const uint8_t*)d_in[1];
  const float* wscale = (const float*)d_in[2];
  float* out = (float*)d_out;

  long long in0 = in_sizes[0];   // M*K
  long long in1 = in_sizes[1];   // N*K
  double kd = sqrt((double)in0 * (double)in1 / (double)out_size);
  long long K = (long long)(kd + 0.5);
  long long M = in0 / K;
  long long N = in1 / K;

  // ws layout: [0,4) amax | [4096,+1MB) qw | [2MB,+64MB) qx
  unsigned int* amax_u = (unsigned int*)d_ws;
  const float* amax_f = (const float*)d_ws;
  uint8_t* qw = (uint8_t*)d_ws + 4096;
  uint8_t* qx = (uint8_t*)d_ws + (2u << 20);

  wconv<<<(unsigned)(in1 / 4 / 256), 256, 0, stream>>>(wraw, qw, amax_u, (int)in1);
  amax_kernel<<<2048, 256, 0, stream>>>(x, (size_t)(in0 / 4), amax_u);
  quant_kernel<<<2048, 256, 0, stream>>>(x, qx, amax_f, (size_t)(in0 / 16));

  dim3 grid((unsigned)((M / BM) * (N / BN)));
  gemm_fp8<<<grid, 256, 0, stream>>>(qx, qw, out, amax_f, wscale,
                                     (int)M, (int)N, (int)K);
}

// Round 7
// 270.775 us; speedup vs baseline: 1.0459x; 1.0459x over previous
//
#include <hip/hip_runtime.h>
#include <hip/hip_fp8.h>
#include <stdint.h>
#include <cmath>

using f32x4 = __attribute__((ext_vector_type(4))) float;
using i32x4 = __attribute__((ext_vector_type(4))) int;
using i32x8 = __attribute__((ext_vector_type(8))) int;

#define FP8MAX 448.0f

// ---------------------------------------------------------------- helpers
__device__ __forceinline__ void gload_lds16(const void* g, void* l) {
  __builtin_amdgcn_global_load_lds(
      (const __attribute__((address_space(1))) unsigned int*)g,
      (__attribute__((address_space(3))) unsigned int*)l,
      16, 0, 0);
}

__device__ __forceinline__ uint8_t to_fp8(float v) {
  __hip_fp8_e4m3 q(fminf(fmaxf(v, -FP8MAX), FP8MAX));  // saturating RNE, OCP e4m3fn
  return q.__x;
}

// ---------------------------------------------------------------- W convert -> fp8 bytes (self-detecting)
// flag 2: float32 of fp8-exact values; 1: bf16; 0: raw fp8 bytes.
// Also zeroes the amax slot (stream-ordered before amax_kernel).
__global__ void wconv(const uint8_t* __restrict__ w, uint8_t* __restrict__ q,
                      unsigned int* __restrict__ amax_u, int n) {
  if (blockIdx.x == 0 && threadIdx.x == 0) amax_u[0] = 0u;

  const float* wf = (const float*)w;
  const unsigned short* wh = (const unsigned short*)w;
  int f32ok = 1, bf16ok = 1;
  for (int i = threadIdx.x; i < 4096; i += 256) {
    float v = wf[i];
    if (!(isfinite(v) && fabsf(v) <= FP8MAX)) f32ok = 0;
    else { __hip_fp8_e4m3 qq(v); if ((float)qq != v) f32ok = 0; }
    float hv = __uint_as_float(((unsigned int)wh[i]) << 16);
    if (!(isfinite(hv) && fabsf(hv) <= FP8MAX)) bf16ok = 0;
    else { __hip_fp8_e4m3 qh(hv); if ((float)qh != hv) bf16ok = 0; }
  }
  __shared__ int sf, sb;
  if (threadIdx.x == 0) { sf = 1; sb = 1; }
  __syncthreads();
  if (!f32ok) atomicAnd(&sf, 0);
  if (!bf16ok) atomicAnd(&sb, 0);
  __syncthreads();
  unsigned int f = sf ? 2u : (sb ? 1u : 0u);

  int i0 = (blockIdx.x * blockDim.x + threadIdx.x) * 4;
  if (i0 >= n) return;
  uint32_t out;
  if (f == 2) {
    float4 v = *(const float4*)((const float*)w + i0);
    out = (uint32_t)to_fp8(v.x) | ((uint32_t)to_fp8(v.y) << 8) |
          ((uint32_t)to_fp8(v.z) << 16) | ((uint32_t)to_fp8(v.w) << 24);
  } else if (f == 1) {
    ushort4 h = *(const ushort4*)((const unsigned short*)w + i0);
    float a = __uint_as_float(((unsigned int)h.x) << 16);
    float b = __uint_as_float(((unsigned int)h.y) << 16);
    float c = __uint_as_float(((unsigned int)h.z) << 16);
    float d = __uint_as_float(((unsigned int)h.w) << 16);
    out = (uint32_t)to_fp8(a) | ((uint32_t)to_fp8(b) << 8) |
          ((uint32_t)to_fp8(c) << 16) | ((uint32_t)to_fp8(d) << 24);
  } else {
    out = *(const uint32_t*)(w + i0);
  }
  *(uint32_t*)(q + i0) = out;
}

// ---------------------------------------------------------------- pass 1: amax = max(|x|)
__global__ void amax_kernel(const float* __restrict__ x, size_t n4,
                            unsigned int* __restrict__ amax_u) {
  const float4* x4 = (const float4*)x;
  float m = 0.0f;
  size_t stride = (size_t)gridDim.x * blockDim.x;
  for (size_t i = (size_t)blockIdx.x * blockDim.x + threadIdx.x; i < n4; i += stride) {
    float4 v = x4[i];
    m = fmaxf(m, fmaxf(fmaxf(fabsf(v.x), fabsf(v.y)),
                       fmaxf(fabsf(v.z), fabsf(v.w))));
  }
  #pragma unroll
  for (int off = 32; off > 0; off >>= 1)
    m = fmaxf(m, __shfl_xor(m, off));
  __shared__ float sm[16];
  int wid = threadIdx.x >> 6;
  if ((threadIdx.x & 63) == 0) sm[wid] = m;
  __syncthreads();
  if (threadIdx.x == 0) {
    int nw = blockDim.x >> 6;
    float r = sm[0];
    for (int i = 1; i < nw; i++) r = fmaxf(r, sm[i]);
    atomicMax(amax_u, __float_as_uint(r));  // non-negative float bits order-preserving
  }
}

// ---------------------------------------------------------------- pass 2: quantize x -> fp8
__global__ void quant_kernel(const float* __restrict__ x,
                             uint8_t* __restrict__ q,
                             const float* __restrict__ amax_p, size_t n16) {
  float amax = fmaxf(amax_p[0], 1e-12f);
  float scale = FP8MAX / amax;        // reference: FP8_MAX / clip(amax)
  const float4* x4 = (const float4*)x;
  uint4* q16 = (uint4*)q;
  size_t stride = (size_t)gridDim.x * blockDim.x;
  for (size_t i = (size_t)blockIdx.x * blockDim.x + threadIdx.x; i < n16; i += stride) {
    uint32_t w[4];
    #pragma unroll
    for (int j = 0; j < 4; j++) {
      float4 v = x4[i * 4 + j];
      w[j] = (uint32_t)to_fp8(v.x * scale) | ((uint32_t)to_fp8(v.y * scale) << 8) |
             ((uint32_t)to_fp8(v.z * scale) << 16) | ((uint32_t)to_fp8(v.w * scale) << 24);
    }
    uint4 o; o.x = w[0]; o.y = w[1]; o.z = w[2]; o.w = w[3];
    q16[i] = o;
  }
}

// ---------------------------------------------------------------- pass 3: MX-fp8 GEMM, counted-vmcnt pipeline
// C[M,N] = s * A[M,K] x B[N,K]^T.  128x128 tile, BK=128, 8 waves (4Mx2N,
// wave tile 32x64), mfma_scale_f32_16x16x128_f8f6f4 with E8M0 0x7F (=1.0).
// T4: double-buffered LDS, raw s_barrier + s_waitcnt vmcnt(4) -- next
// tile's 4 loads stay IN FLIGHT across the barrier (m218: counted-vs-drain0
// is the pipeline gain; R6 showed __syncthreads dbuf = null).
// T2 swizzle under global_load_lds (rule #21): linear LDS dest, global
// source 16B-chunk ^= (row&7), reads XOR the same way.
// T5: setprio(1) around the MFMA cluster (load-issuing vs MFMA role split).
#define BM 128
#define BN 128
#define BK 128

__global__ __launch_bounds__(512, 4) void gemm_fp8(
    const uint8_t* __restrict__ A,   // [M,K] fp8
    const uint8_t* __restrict__ B,   // [N,K] fp8
    float* __restrict__ C,           // [M,N] f32
    const float* __restrict__ amax_p,
    const float* __restrict__ wscale_p,
    int M, int N, int K) {
  __shared__ uint8_t lds[2][2][BM * BK];  // [dbuf][A/B][16 KB] = 64 KB

  // bijective XCD swizzle (gridDim % 8 == 0); 8 consecutive swz share bm
  // (same A-strip) -> same XCD -> strip fetched from HBM once per XCD.
  int nwg = gridDim.x;
  int cpx = nwg >> 3;
  int swz = (blockIdx.x & 7) * cpx + (blockIdx.x >> 3);

  int nstrips = N / BN;               // 8
  int bm = (swz / nstrips) * BM;
  int bn = (swz % nstrips) * BN;

  int t = threadIdx.x;                // 0..511
  int lane = t & 63;
  int wave = t >> 6;                  // 0..7
  int wm = (wave >> 1) * 32;          // 0,32,64,96
  int wn = (wave & 1) * 64;           // 0,64

  float amax = fmaxf(amax_p[0], 1e-12f);
  float scale = FP8MAX / amax;
  float s = (1.0f / scale) * wscale_p[0];   // inv_act_scale * weight_scale

  f32x4 acc[2][4] = {};

  // staging: pass p in {0,1} covers rows p*64 + (t>>3); 16B chunk ct = t&7.
  // LDS linear dest p*8192 + t*16 (= wave-uniform base + lane*16);
  // global chunk pre-swizzled (ct ^ (row&7)).
  const int rt = t >> 3;
  const int ct = t & 7;

  // fragment read constants
  const int lr = lane & 15;           // row-in-fragment
  const int x7 = lr & 7;              // frag rows have row&7 == lr&7
  const int g2 = (lane >> 4) << 1;    // chunk pair base: 0,2,4,6
  const int c0 = ((g2 ^ x7) << 4);
  const int c1 = (((g2 + 1) ^ x7) << 4);
  int abase[2], bbase[4];
  #pragma unroll
  for (int i = 0; i < 2; i++) abase[i] = (wm + i * 16 + lr) * BK;
  #pragma unroll
  for (int j = 0; j < 4; j++) bbase[j] = (wn + j * 16 + lr) * BK;

  auto stage = [&](int buf, int kt) {   // 4 gload_lds per thread
    int k0 = kt * BK;
    #pragma unroll
    for (int p = 0; p < 2; ++p) {
      int r = p * 64 + rt;
      int gc = (ct ^ (r & 7)) * 16;
      gload_lds16(A + (size_t)(bm + r) * K + k0 + gc, &lds[buf][0][p * 8192 + t * 16]);
      gload_lds16(B + (size_t)(bn + r) * K + k0 + gc, &lds[buf][1][p * 8192 + t * 16]);
    }
  };

  auto compute = [&](int buf) {
    const uint8_t* baseA = &lds[buf][0][0];
    const uint8_t* baseB = &lds[buf][1][0];
    i32x8 af[2], bf[4];
    #pragma unroll
    for (int i = 0; i < 2; i++) {
      i32x4 lo = *(const i32x4*)(baseA + abase[i] + c0);
      i32x4 hi = *(const i32x4*)(baseA + abase[i] + c1);
      af[i] = (i32x8){lo.x, lo.y, lo.z, lo.w, hi.x, hi.y, hi.z, hi.w};
    }
    #pragma unroll
    for (int j = 0; j < 4; j++) {
      i32x4 lo = *(const i32x4*)(baseB + bbase[j] + c0);
      i32x4 hi = *(const i32x4*)(baseB + bbase[j] + c1);
      bf[j] = (i32x8){lo.x, lo.y, lo.z, lo.w, hi.x, hi.y, hi.z, hi.w};
    }
    __builtin_amdgcn_s_setprio(1);
    #pragma unroll
    for (int j = 0; j < 4; j++)
      #pragma unroll
      for (int i = 0; i < 2; i++)
        acc[i][j] = __builtin_amdgcn_mfma_scale_f32_16x16x128_f8f6f4(
            af[i], bf[j], acc[i][j],
            0 /*A=fp8*/, 0 /*B=fp8*/,
            0, 0x7f7f7f7f,   // scale_A: E8M0 1.0
            0, 0x7f7f7f7f);  // scale_B: E8M0 1.0
    __builtin_amdgcn_s_setprio(0);
  };

  const int KITERS = K / BK;          // 8
  stage(0, 0);                        // 4 loads in flight

  for (int it = 0; it < KITERS; ++it) {
    int cur = it & 1;
    if (it + 1 < KITERS) {
      stage(cur ^ 1, it + 1);                         // +4 loads (total 8)
      asm volatile("s_waitcnt vmcnt(4)" ::: "memory"); // cur's 4 landed; next's fly on
    } else {
      asm volatile("s_waitcnt vmcnt(0)" ::: "memory");
    }
    __builtin_amdgcn_s_barrier();        // all waves' cur loads landed
    __builtin_amdgcn_sched_barrier(0);   // pin ds_reads below the barrier
    compute(cur);
    __builtin_amdgcn_s_barrier();        // all waves done reading cur before overwrite
  }

  // epilogue: C/D layout col=lane&15, row=(lane>>4)*4+reg (shape-determined)
  #pragma unroll
  for (int i = 0; i < 2; i++) {
    #pragma unroll
    for (int j = 0; j < 4; j++) {
      int row = bm + wm + i * 16 + (lane >> 4) * 4;
      int col = bn + wn + j * 16 + (lane & 15);
      #pragma unroll
      for (int r = 0; r < 4; r++)
        C[(size_t)(row + r) * N + col] = acc[i][j][r] * s;
    }
  }
}

// ---------------------------------------------------------------- launch
extern "C" void kernel_launch(void* const* d_in, const int* in_sizes, int n_in,
                              void* d_out, int out_size, void* d_ws, size_t ws_size,
                              hipStream_t stream) {
  const float* x = (const float*)d_in[0];
  const uint8_t* wraw = (const uint8_t*)d_in[1];
  const float* wscale = (const float*)d_in[2];
  float* out = (float*)d_out;

  long long in0 = in_sizes[0];   // M*K
  long long in1 = in_sizes[1];   // N*K
  double kd = sqrt((double)in0 * (double)in1 / (double)out_size);
  long long K = (long long)(kd + 0.5);
  long long M = in0 / K;
  long long N = in1 / K;

  // ws layout: [0,4) amax | [4096,+1MB) qw | [2MB,+64MB) qx
  unsigned int* amax_u = (unsigned int*)d_ws;
  const float* amax_f = (const float*)d_ws;
  uint8_t* qw = (uint8_t*)d_ws + 4096;
  uint8_t* qx = (uint8_t*)d_ws + (2u << 20);

  wconv<<<(unsigned)(in1 / 4 / 256), 256, 0, stream>>>(wraw, qw, amax_u, (int)in1);
  amax_kernel<<<2048, 256, 0, stream>>>(x, (size_t)(in0 / 4), amax_u);
  quant_kernel<<<2048, 256, 0, stream>>>(x, qx, amax_f, (size_t)(in0 / 16));

  dim3 grid((unsigned)((M / BM) * (N / BN)));
  gemm_fp8<<<grid, 512, 0, stream>>>(qx, qw, out, amax_f, wscale,
                                     (int)M, (int)N, (int)K);
}